// Round 1
// baseline (187.122 us; speedup 1.0000x reference)
//
#include <hip/hip_runtime.h>
#include <hip/hip_bf16.h>

// SVXSoftmax: cos = norm(input) @ norm(weight)^T ; margin transform ; *32
// B=512, D=512, C=100000.  out[512][100000] f32.

#define S_SCALE 32.0f
#define MARGIN  0.35f
#define T_BOOST 0.2f
#define EPSN    1e-12f

constexpr int Bn = 512;      // batch
constexpr int Dn = 512;      // dim
constexpr int Cn = 100000;   // classes

constexpr int BM = 256, BN = 128, BK = 32;
constexpr int PAD = 40;      // LDS row stride (bf16 elems); 40*2=80B, 16B-aligned, 2-way-max bank aliasing

typedef __attribute__((ext_vector_type(8))) short bf16x8;
typedef __attribute__((ext_vector_type(4))) float f32x4;

static __device__ inline unsigned short f32_bf16(float f) {
    unsigned int u = __float_as_uint(f);
    u += 0x7FFFu + ((u >> 16) & 1u);     // round-to-nearest-even
    return (unsigned short)(u >> 16);
}

// ---------------- kernel 1: input norms, gt[b], bf16 normalized input ----------------
__global__ __launch_bounds__(256) void prep_kernel(const float* __restrict__ in,
                                                   const float* __restrict__ w,
                                                   const int* __restrict__ label,
                                                   float* __restrict__ gt,
                                                   unsigned short* __restrict__ in_h) {
    int b = blockIdx.x;
    int t = threadIdx.x;
    const float* irow = in + (size_t)b * Dn;
    int lab = label[b];
    const float* wrow = w + (size_t)lab * Dn;
    float x0 = irow[t], x1 = irow[t + 256];
    float y0 = wrow[t], y1 = wrow[t + 256];
    float s_ii = x0 * x0 + x1 * x1;
    float s_ww = y0 * y0 + y1 * y1;
    float s_iw = x0 * y0 + x1 * y1;
    #pragma unroll
    for (int off = 32; off; off >>= 1) {
        s_ii += __shfl_xor(s_ii, off);
        s_ww += __shfl_xor(s_ww, off);
        s_iw += __shfl_xor(s_iw, off);
    }
    __shared__ float r0[4], r1[4], r2[4], bc[1];
    int wid = t >> 6;
    if ((t & 63) == 0) { r0[wid] = s_ii; r1[wid] = s_ww; r2[wid] = s_iw; }
    __syncthreads();
    if (t == 0) {
        float a = r0[0] + r0[1] + r0[2] + r0[3];
        float c = r1[0] + r1[1] + r1[2] + r1[3];
        float d = r2[0] + r2[1] + r2[2] + r2[3];
        float inv_i = 1.0f / fmaxf(sqrtf(a), EPSN);
        float g = d * inv_i / fmaxf(sqrtf(c), EPSN);
        g = fminf(fmaxf(g, -1.0f), 1.0f);
        gt[b] = g;
        bc[0] = inv_i;
    }
    __syncthreads();
    float inv_i = bc[0];
    in_h[(size_t)b * Dn + t]       = f32_bf16(x0 * inv_i);
    in_h[(size_t)b * Dn + t + 256] = f32_bf16(x1 * inv_i);
}

// ---------------- kernel 2: weight row inverse norms (wave per row) ----------------
__global__ __launch_bounds__(256) void winv_kernel(const float* __restrict__ w,
                                                   float* __restrict__ winv) {
    int row  = blockIdx.x * 4 + (threadIdx.x >> 6);
    int lane = threadIdx.x & 63;
    const float* wr = w + (size_t)row * Dn;
    f32x4 v0 = *(const f32x4*)(wr + lane * 4);
    f32x4 v1 = *(const f32x4*)(wr + 256 + lane * 4);
    float s = 0.f;
    #pragma unroll
    for (int i = 0; i < 4; ++i) s += v0[i] * v0[i] + v1[i] * v1[i];
    #pragma unroll
    for (int off = 32; off; off >>= 1) s += __shfl_xor(s, off);
    if (lane == 0) winv[row] = 1.0f / fmaxf(sqrtf(s), EPSN);
}

// ---------------- kernel 3: fused normalized GEMM + margin epilogue ----------------
__global__ __launch_bounds__(512) void gemm_kernel(const unsigned short* __restrict__ in_h,
                                                   const float* __restrict__ w,
                                                   const float* __restrict__ winv,
                                                   const float* __restrict__ gt,
                                                   const int* __restrict__ label,
                                                   float* __restrict__ out) {
    __shared__ unsigned short As[BM * PAD];   // 20480 B
    __shared__ unsigned short Bs[BN * PAD];   // 10240 B

    int bm = blockIdx.x;       // 0..1   (M fast => consecutive blocks share the W tile)
    int bn = blockIdx.y;       // 0..781
    int t = threadIdx.x;
    int wid = t >> 6, lane = t & 63;
    int wm = wid >> 1, wn = wid & 1;          // 4x2 wave grid, each wave 64x64
    int l15 = lane & 15, lk = lane >> 4;      // frag row-in-tile / k-group

    f32x4 acc[4][4] = {};

    // staging coords
    int arow = t >> 2, akg = t & 3;           // A chunk t ; second chunk t+512
    int brow = t >> 2, bkg = t & 3;           // B: 128 rows x 4 k-groups
    int bc_glob = bn * BN + brow;
    if (bc_glob >= Cn) bc_glob = Cn - 1;      // clamp; results discarded by epilogue guard
    const float* bsrc_row = w + (size_t)bc_glob * Dn;
    float bscale = winv[bc_glob];

    for (int kt = 0; kt < Dn; kt += BK) {
        // ---- stage A (bf16 normalized input, 256x32) ----
        {
            bf16x8 v = *(const bf16x8*)(in_h + ((size_t)(bm * BM + arow) * Dn + kt + akg * 8));
            *(bf16x8*)&As[arow * PAD + akg * 8] = v;
            int row2 = arow + 128;
            bf16x8 v2 = *(const bf16x8*)(in_h + ((size_t)(bm * BM + row2) * Dn + kt + akg * 8));
            *(bf16x8*)&As[row2 * PAD + akg * 8] = v2;
        }
        // ---- stage B (f32 weight -> normalize -> bf16, 128x32) ----
        {
            const float* src = bsrc_row + kt + bkg * 8;
            f32x4 f0 = *(const f32x4*)src;
            f32x4 f1 = *(const f32x4*)(src + 4);
            bf16x8 hv;
            #pragma unroll
            for (int i = 0; i < 4; ++i) {
                hv[i]     = (short)f32_bf16(f0[i] * bscale);
                hv[4 + i] = (short)f32_bf16(f1[i] * bscale);
            }
            *(bf16x8*)&Bs[brow * PAD + bkg * 8] = hv;
        }
        __syncthreads();
        bf16x8 a[4], bb[4];
        #pragma unroll
        for (int mf = 0; mf < 4; ++mf)
            a[mf] = *(const bf16x8*)&As[(wm * 64 + mf * 16 + l15) * PAD + lk * 8];
        #pragma unroll
        for (int nf = 0; nf < 4; ++nf)
            bb[nf] = *(const bf16x8*)&Bs[(wn * 64 + nf * 16 + l15) * PAD + lk * 8];
        #pragma unroll
        for (int mf = 0; mf < 4; ++mf)
            #pragma unroll
            for (int nf = 0; nf < 4; ++nf)
                acc[mf][nf] = __builtin_amdgcn_mfma_f32_16x16x32_bf16(a[mf], bb[nf], acc[mf][nf], 0, 0, 0);
        __syncthreads();
    }

    // ---- epilogue: clamp, margin transform, label scatter, scale ----
    #pragma unroll
    for (int mf = 0; mf < 4; ++mf) {
        int brow_base = bm * BM + wm * 64 + mf * 16 + lk * 4;
        #pragma unroll
        for (int r = 0; r < 4; ++r) {
            int b_row = brow_base + r;
            float g   = gt[b_row];
            int lab   = label[b_row];
            float thr = g - MARGIN;
            float gv  = thr * S_SCALE;
            size_t obase = (size_t)b_row * Cn;
            #pragma unroll
            for (int nf = 0; nf < 4; ++nf) {
                int c = bn * BN + wn * 64 + nf * 16 + l15;
                if (c < Cn) {
                    float cosv = acc[mf][nf][r];
                    cosv = fminf(fmaxf(cosv, -1.0f), 1.0f);
                    float o;
                    if (c == lab)          o = gv;
                    else if (cosv > thr)   o = ((T_BOOST + 1.0f) * cosv + T_BOOST) * S_SCALE;
                    else                   o = cosv * S_SCALE;
                    out[obase + c] = o;
                }
            }
        }
    }
}

extern "C" void kernel_launch(void* const* d_in, const int* in_sizes, int n_in,
                              void* d_out, int out_size, void* d_ws, size_t ws_size,
                              hipStream_t stream) {
    const float* in  = (const float*)d_in[0];
    const float* w   = (const float*)d_in[1];
    const int* label = (const int*)d_in[2];
    float* out = (float*)d_out;

    char* ws = (char*)d_ws;
    float* gt   = (float*)ws;                        // 512 f32
    float* winv = (float*)(ws + 4096);               // 100000 f32 = 400000 B
    unsigned short* in_h = (unsigned short*)(ws + 4096 + 400384); // 512*512 bf16 = 524288 B
    // total ws use: ~929 KB

    prep_kernel<<<dim3(Bn), dim3(256), 0, stream>>>(in, w, label, gt, in_h);
    winv_kernel<<<dim3(Cn / 4), dim3(256), 0, stream>>>(w, winv);
    dim3 grid(2, (Cn + BN - 1) / BN);   // (M-blocks fast, 782 N-blocks)
    gemm_kernel<<<grid, dim3(512), 0, stream>>>(in_h, w, winv, gt, label, out);
}